// Round 5
// baseline (2832.840 us; speedup 1.0000x reference)
//
#include <hip/hip_runtime.h>
#include <hip/hip_bf16.h>
#include <math.h>

// ---------------------------------------------------------------------------
// Weight pre-transposes (run every call; ~300K elements total).
// Wx (3,3,Cin,Cout) -> wxT[(tap*Cout + co)*CIN_P + c]  (c zero-padded to CIN_P)
// Wh (3,3,F,4F)     -> whT[((tap*4+g)*F + f)*F + c]
// These make the conv/lstm inner-loop weight fetches float4 (16B) loads.
// ---------------------------------------------------------------------------
__global__ void transpose_wx(const float* __restrict__ src, float* __restrict__ dst,
                             int Cin, int CinP, int Cout)
{
  int i = blockIdx.x * 256 + threadIdx.x;
  int total = 9 * Cout * CinP;
  if (i >= total) return;
  int c = i % CinP; int rem = i / CinP;
  int co = rem % Cout; int tap = rem / Cout;
  dst[i] = (c < Cin) ? src[((size_t)tap * Cin + c) * Cout + co] : 0.f;
}

__global__ void transpose_wh(const float* __restrict__ src, float* __restrict__ dst, int F)
{
  int i = blockIdx.x * 256 + threadIdx.x;
  int total = 9 * 4 * F * F;
  if (i >= total) return;
  int c = i % F; int rem = i / F;
  int f = rem % F; rem /= F;
  int g = rem % 4; int tap = rem / 4;
  dst[i] = src[((size_t)tap * F + c) * 4 * F + g * F + f];
}

// ---------------------------------------------------------------------------
// Direct 3x3 'SAME' conv, NHWC, fp32, with bias. Register blocking: thread
// computes NG output channels (co = tid%COL + g*COL) for PPT positions.
// Weights pre-transposed -> NG float4 loads per c4-iter.
// NOTE: `#pragma unroll 1` on the channel loop is load-bearing (R0 spill).
// ---------------------------------------------------------------------------
template<int H, int W, int Cin, int Cout, int TH, int TW, int COL, int NG>
__global__ __launch_bounds__(256) void conv3x3_bias(
    const float* __restrict__ in, const float* __restrict__ wtT,
    const float* __restrict__ bias, float* __restrict__ out)
{
  static_assert(COL * NG == Cout, "cout coverage");
  constexpr int CIN_P = (Cin % 4 == 0) ? Cin : ((Cin + 3) / 4) * 4;
  constexpr int TILES_X = W / TW, TILES_Y = H / TH;
  constexpr int PAD_W = TW + 2, PAD_H = TH + 2;
  constexpr int LDS_N = PAD_H * PAD_W * CIN_P;
  constexpr int NPG = 256 / COL;
  constexpr int PPT = TH * TW / NPG;
  __shared__ __align__(16) float tile[LDS_N];

  int blk = blockIdx.x;
  int n = blk / (TILES_X * TILES_Y);
  int trem = blk % (TILES_X * TILES_Y);
  int ty = trem / TILES_X, tx = trem % TILES_X;
  int y0 = ty * TH, x0 = tx * TW;
  const float* inN = in + (size_t)n * H * W * Cin;

  for (int i = threadIdx.x; i < LDS_N; i += 256) {
    int ci = i % CIN_P; int rem = i / CIN_P;
    int xx = rem % PAD_W; int yy = rem / PAD_W;
    int gy = y0 + yy - 1, gx = x0 + xx - 1;
    float v = 0.f;
    if (ci < Cin && gy >= 0 && gy < H && gx >= 0 && gx < W)
      v = inN[((size_t)gy * W + gx) * Cin + ci];
    tile[i] = v;
  }
  __syncthreads();

  int cobase = threadIdx.x % COL;
  int pg = threadIdx.x / COL;
  float* outN = out + (size_t)n * H * W * Cout;

  float acc[NG][PPT];
#pragma unroll
  for (int g = 0; g < NG; ++g) {
    float bco = bias[g * COL + cobase];
#pragma unroll
    for (int j = 0; j < PPT; ++j) acc[g][j] = bco;
  }

#pragma unroll
  for (int kh = 0; kh < 3; ++kh)
#pragma unroll
  for (int kw = 0; kw < 3; ++kw) {
    const float* wtap = wtT + (size_t)(kh * 3 + kw) * Cout * CIN_P;
#pragma unroll 1
    for (int c4 = 0; c4 < CIN_P; c4 += 4) {
      float4 w[NG];
#pragma unroll
      for (int g = 0; g < NG; ++g)
        w[g] = *(const float4*)&wtap[(size_t)(g * COL + cobase) * CIN_P + c4];
#pragma unroll
      for (int j = 0; j < PPT; ++j) {
        int p = pg * PPT + j;
        int ly = p / TW, lx = p % TW;
        const float4 h4 = *(const float4*)&tile[((ly + kh) * PAD_W + (lx + kw)) * CIN_P + c4];
#pragma unroll
        for (int g = 0; g < NG; ++g)
          acc[g][j] += h4.x * w[g].x + h4.y * w[g].y + h4.z * w[g].z + h4.w * w[g].w;
      }
    }
  }

#pragma unroll
  for (int j = 0; j < PPT; ++j) {
    int p = pg * PPT + j;
    int ly = p / TW, lx = p % TW;
    float* op = &outN[((size_t)(y0 + ly) * W + (x0 + lx)) * Cout + cobase];
#pragma unroll
    for (int g = 0; g < NG; ++g) op[g * COL] = acc[g][j];
  }
}

// ---------------------------------------------------------------------------
// One ConvLSTM timestep: z = gx[t] + conv3x3(h_prev, WhT); gates i,f,c,o;
// c = hs(zf)*c + hs(zi)*tanh(zc); h = hs(zo)*tanh(c).
// Thread owns one f across all 4 gates, NP positions. Weights pre-transposed
// -> 4 float4 loads per c4-iter (was 16 scalar loads).
// ---------------------------------------------------------------------------
__device__ __forceinline__ float hsig(float x) {
  return fminf(fmaxf(0.2f * x + 0.5f, 0.f), 1.f);
}

template<int H, int W, int F, int TH, int TW>
__global__ __launch_bounds__(256) void lstm_step(
    const float* __restrict__ gx, long gx_bstride,     // pre-offset to slice t
    const float* __restrict__ hprev, long hp_bstride,  // null when first
    const float* __restrict__ whT,                     // [(tap*4+g)*F + f][F]
    float* __restrict__ c,
    float* __restrict__ hout, long ho_bstride,
    int first)
{
  constexpr int TILES_X = W / TW, TILES_Y = H / TH;
  constexpr int PAD_W = TW + 2, PAD_H = TH + 2;
  constexpr int LDS_N = PAD_H * PAD_W * F;
  __shared__ __align__(16) float tile[LDS_N];

  int blk = blockIdx.x;
  int b = blk / (TILES_X * TILES_Y);
  int trem = blk % (TILES_X * TILES_Y);
  int ty = trem / TILES_X, tx = trem % TILES_X;
  int y0 = ty * TH, x0 = tx * TW;

  if (first) {
    for (int i = threadIdx.x; i < LDS_N; i += 256) tile[i] = 0.f;
  } else {
    const float* hb = hprev + (size_t)b * hp_bstride;
    for (int i = threadIdx.x; i < LDS_N; i += 256) {
      int ci = i % F; int rem = i / F;
      int xx = rem % PAD_W, yy = rem / PAD_W;
      int gy = y0 + yy - 1, gxp = x0 + xx - 1;
      float v = 0.f;
      if (gy >= 0 && gy < H && gxp >= 0 && gxp < W)
        v = hb[((size_t)gy * W + gxp) * F + ci];
      tile[i] = v;
    }
  }
  __syncthreads();

  constexpr int G = 256 / F;     // position-groups
  constexpr int P = TH * TW;
  constexpr int NP = P / G;      // positions per thread
  int f = threadIdx.x % F;
  int pg = threadIdx.x / F;

  float acc[4][NP];
  const float* gxb = gx + (size_t)b * gx_bstride;
#pragma unroll
  for (int j = 0; j < NP; ++j) {
    int p = pg * NP + j;
    int gy = y0 + p / TW, gxp = x0 + p % TW;
    size_t base = ((size_t)gy * W + gxp) * 4 * F;
#pragma unroll
    for (int g = 0; g < 4; ++g) acc[g][j] = gxb[base + g * F + f];
  }

#pragma unroll
  for (int kh = 0; kh < 3; ++kh)
#pragma unroll
  for (int kw = 0; kw < 3; ++kw) {
    // weight rows for this tap, this f, each gate: contiguous in c
    const float* w0p = whT + ((size_t)((kh * 3 + kw) * 4 + 0) * F + f) * F;
    const float* w1p = whT + ((size_t)((kh * 3 + kw) * 4 + 1) * F + f) * F;
    const float* w2p = whT + ((size_t)((kh * 3 + kw) * 4 + 2) * F + f) * F;
    const float* w3p = whT + ((size_t)((kh * 3 + kw) * 4 + 3) * F + f) * F;
#pragma unroll 1
    for (int c4 = 0; c4 < F; c4 += 4) {
      float4 h4[NP];
#pragma unroll
      for (int j = 0; j < NP; ++j) {
        int p = pg * NP + j;
        int ly = p / TW, lx = p % TW;
        h4[j] = *(const float4*)&tile[((ly + kh) * PAD_W + (lx + kw)) * F + c4];
      }
      float4 w0 = *(const float4*)&w0p[c4];
      float4 w1 = *(const float4*)&w1p[c4];
      float4 w2 = *(const float4*)&w2p[c4];
      float4 w3 = *(const float4*)&w3p[c4];
#pragma unroll
      for (int j = 0; j < NP; ++j) {
        acc[0][j] += h4[j].x * w0.x + h4[j].y * w0.y + h4[j].z * w0.z + h4[j].w * w0.w;
        acc[1][j] += h4[j].x * w1.x + h4[j].y * w1.y + h4[j].z * w1.z + h4[j].w * w1.w;
        acc[2][j] += h4[j].x * w2.x + h4[j].y * w2.y + h4[j].z * w2.z + h4[j].w * w2.w;
        acc[3][j] += h4[j].x * w3.x + h4[j].y * w3.y + h4[j].z * w3.z + h4[j].w * w3.w;
      }
    }
  }

  float* cb = c + (size_t)b * H * W * F;
  float* hb2 = hout + (size_t)b * ho_bstride;
#pragma unroll
  for (int j = 0; j < NP; ++j) {
    int p = pg * NP + j;
    int gy = y0 + p / TW, gxp = x0 + p % TW;
    size_t idx = ((size_t)gy * W + gxp) * F + f;
    float zi = acc[0][j], zf = acc[1][j], zc = acc[2][j], zo = acc[3][j];
    float cold = first ? 0.f : cb[idx];
    float cn = hsig(zf) * cold + hsig(zi) * tanhf(zc);
    cb[idx] = cn;
    hb2[idx] = hsig(zo) * tanhf(cn);
  }
}

// ---------------------------------------------------------------------------
// BatchNorm (affine, eps=1e-3) + 2x2 spatial max.
// ---------------------------------------------------------------------------
__global__ void bnpool_kernel(const float* __restrict__ in,
                              const float* __restrict__ g, const float* __restrict__ be,
                              const float* __restrict__ m, const float* __restrict__ v,
                              float* __restrict__ out, int total, int H, int W, int F)
{
  int i = blockIdx.x * 256 + threadIdx.x;
  if (i >= total) return;
  int f = i % F; int rem = i / F;
  int x = rem % (W / 2); rem /= (W / 2);
  int y = rem % (H / 2); int nt = rem / (H / 2);
  float scale = g[f] * rsqrtf(v[f] + 1e-3f);
  float shift = be[f] - m[f] * scale;
  const float* base = in + (((size_t)nt * H + 2 * y) * W + 2 * x) * F + f;
  float a0 = base[0] * scale + shift;
  float a1 = base[F] * scale + shift;
  float a2 = base[(size_t)W * F] * scale + shift;
  float a3 = base[(size_t)W * F + F] * scale + shift;
  out[i] = fmaxf(fmaxf(a0, a1), fmaxf(a2, a3));
}

// (8,16,16,64) -> (8,8,8,64) flattened to (8,4096)
__global__ void poolhw_kernel(const float* __restrict__ in, float* __restrict__ out, int total)
{
  int i = blockIdx.x * 256 + threadIdx.x;
  if (i >= total) return;
  int f = i % 64; int rem = i / 64;
  int x = rem % 8; rem /= 8;
  int y = rem % 8; int b = rem / 8;
  const float* base = in + (((size_t)b * 16 + 2 * y) * 16 + 2 * x) * 64 + f;
  float a0 = base[0], a1 = base[64], a2 = base[16 * 64], a3 = base[16 * 64 + 64];
  out[i] = fmaxf(fmaxf(a0, a1), fmaxf(a2, a3));
}

// ---------------------------------------------------------------------------
// Dense (8,K)@(K,N): k-split partials + reduce (no atomics).
// ---------------------------------------------------------------------------
__global__ __launch_bounds__(256) void dense_partial(
    const float* __restrict__ x, const float* __restrict__ w,
    float* __restrict__ part, int K, int N, int kchunk)
{
  extern __shared__ __align__(16) float xs[];  // kchunk*8, layout [kk][b]
  int kb = blockIdx.y;
  int k0 = kb * kchunk;
  int klen = min(kchunk, K - k0);
  for (int i = threadIdx.x; i < klen * 8; i += 256) {
    int kk = i >> 3, b = i & 7;
    xs[i] = x[(size_t)b * K + k0 + kk];
  }
  __syncthreads();
  int co = blockIdx.x * 256 + threadIdx.x;
  if (co >= N) return;
  float acc[8];
#pragma unroll
  for (int b = 0; b < 8; ++b) acc[b] = 0.f;
  const float4* xs4 = (const float4*)xs;
  const float* wp = w + (size_t)k0 * N + co;
#pragma unroll 4
  for (int kk = 0; kk < klen; ++kk) {
    float wv = wp[(size_t)kk * N];
    float4 lo = xs4[kk * 2], hi = xs4[kk * 2 + 1];
    acc[0] += lo.x * wv; acc[1] += lo.y * wv;
    acc[2] += lo.z * wv; acc[3] += lo.w * wv;
    acc[4] += hi.x * wv; acc[5] += hi.y * wv;
    acc[6] += hi.z * wv; acc[7] += hi.w * wv;
  }
#pragma unroll
  for (int b = 0; b < 8; ++b)
    part[((size_t)kb * 8 + b) * N + co] = acc[b];
}

__global__ __launch_bounds__(256) void dense_reduce(
    const float* __restrict__ part, const float* __restrict__ bias,
    float* __restrict__ out, int N, int S)
{
  int co = blockIdx.x * 256 + threadIdx.x;
  int b = blockIdx.y;
  if (co >= N) return;
  float acc = bias[co];
#pragma unroll 4
  for (int kb = 0; kb < S; ++kb)
    acc += part[((size_t)kb * 8 + b) * N + co];
  out[(size_t)b * N + co] = acc;
}

// Direct small dense: one thread per (b,co). Used for 1000->100.
__global__ void dense_small(const float* __restrict__ x, const float* __restrict__ w,
                            const float* __restrict__ bias, float* __restrict__ out,
                            int K, int N, int total)
{
  int idx = blockIdx.x * 256 + threadIdx.x;
  if (idx >= total) return;
  int b = idx / N, co = idx % N;
  float acc = bias[co];
  const float* xb = x + (size_t)b * K;
#pragma unroll 4
  for (int k = 0; k < K; ++k) acc += xb[k] * w[(size_t)k * N + co];
  out[idx] = acc;
}

// Final (8,100)@(100,10)+b4 then @(10,1)+bc -> (8,1)
__global__ void dense_tail(const float* __restrict__ d3,
                           const float* __restrict__ w4, const float* __restrict__ b4,
                           const float* __restrict__ wc, const float* __restrict__ bc,
                           float* __restrict__ out)
{
  __shared__ float d4[8][10];
  int t = threadIdx.x;
  if (t < 80) {
    int b = t / 10, co = t % 10;
    float acc = b4[co];
    for (int k = 0; k < 100; ++k) acc += d3[b * 100 + k] * w4[k * 10 + co];
    d4[b][co] = acc;
  }
  __syncthreads();
  if (t < 8) {
    float acc = bc[0];
    for (int j = 0; j < 10; ++j) acc += d4[t][j] * wc[j];
    out[t] = acc;
  }
}

// ---------------------------------------------------------------------------
extern "C" void kernel_launch(void* const* d_in, const int* in_sizes, int n_in,
                              void* d_out, int out_size, void* d_ws, size_t ws_size,
                              hipStream_t stream)
{
  const float* x   = (const float*)d_in[0];
  const float* W1x = (const float*)d_in[1];
  const float* W1h = (const float*)d_in[2];
  const float* b1  = (const float*)d_in[3];
  const float* g1  = (const float*)d_in[4];
  const float* be1 = (const float*)d_in[5];
  const float* m1  = (const float*)d_in[6];
  const float* v1  = (const float*)d_in[7];
  const float* W2x = (const float*)d_in[8];
  const float* W2h = (const float*)d_in[9];
  const float* b2  = (const float*)d_in[10];
  const float* g2  = (const float*)d_in[11];
  const float* be2 = (const float*)d_in[12];
  const float* m2  = (const float*)d_in[13];
  const float* v2  = (const float*)d_in[14];
  const float* W3x = (const float*)d_in[15];
  const float* W3h = (const float*)d_in[16];
  const float* b3  = (const float*)d_in[17];
  const float* Wd1 = (const float*)d_in[18];
  const float* bd1 = (const float*)d_in[19];
  const float* Wd2 = (const float*)d_in[20];
  const float* bd2 = (const float*)d_in[21];
  const float* Wd3 = (const float*)d_in[22];
  const float* bd3 = (const float*)d_in[23];
  const float* Wd4 = (const float*)d_in[24];
  const float* bd4 = (const float*)d_in[25];
  const float* Wc  = (const float*)d_in[26];
  const float* bc  = (const float*)d_in[27];

  // workspace layout (bytes, 256-aligned), lifetime-based reuse
  char* ws = (char*)d_ws;
  size_t off = 0;
  auto alloc = [&](size_t bytes) { size_t r = off; off = (off + bytes + 255) & ~(size_t)255; return r; };
  size_t oR0    = alloc(100663296);  // gx1 -> gx2 -> gx3; then part1/part2 for dense
  size_t oR1    = alloc(25165824);   // hseq1 -> hseq2
  size_t oR2    = alloc(6291456);    // pool1 -> pool2
  size_t oR3    = alloc(2097152);    // c buffer
  size_t oh3a   = alloc(524288);
  size_t oh3b   = alloc(524288);
  size_t oflat  = alloc(131072);
  size_t od1    = alloc(320000);
  size_t od2    = alloc(32000);
  size_t od3    = alloc(3200);
  size_t oWx1T  = alloc(9216);      // 9*64*4
  size_t oWx2T  = alloc(73728);     // 9*128*16
  size_t oWx3T  = alloc(294912);    // 9*256*32
  size_t oWh1T  = alloc(36864);     // 9*4*16*16
  size_t oWh2T  = alloc(147456);    // 9*4*32*32
  size_t oWh3T  = alloc(589824);    // 9*4*64*64
  (void)ws_size; (void)in_sizes; (void)n_in; (void)out_size;

  float* gx1   = (float*)(ws + oR0);
  float* gx2   = (float*)(ws + oR0);
  float* gx3   = (float*)(ws + oR0);
  float* part1 = (float*)(ws + oR0);             // 64*8*10000*4 = 20.5 MB (gx dead)
  float* part2 = (float*)(ws + oR0 + 33554432);  // 125*8*1000*4 = 4 MB
  float* hseq1 = (float*)(ws + oR1);
  float* hseq2 = (float*)(ws + oR1);
  float* pool1 = (float*)(ws + oR2);
  float* pool2 = (float*)(ws + oR2);
  float* cbuf  = (float*)(ws + oR3);
  float* h3a   = (float*)(ws + oh3a);
  float* h3b   = (float*)(ws + oh3b);
  float* flat  = (float*)(ws + oflat);
  float* d1    = (float*)(ws + od1);
  float* d2    = (float*)(ws + od2);
  float* d3b   = (float*)(ws + od3);
  float* Wx1T  = (float*)(ws + oWx1T);
  float* Wx2T  = (float*)(ws + oWx2T);
  float* Wx3T  = (float*)(ws + oWx3T);
  float* Wh1T  = (float*)(ws + oWh1T);
  float* Wh2T  = (float*)(ws + oWh2T);
  float* Wh3T  = (float*)(ws + oWh3T);

  const int B = 8, T = 12;

  // ---- Weight transposes (tiny) ----
  transpose_wx<<<(9 * 64 * 4 + 255) / 256, 256, 0, stream>>>(W1x, Wx1T, 3, 4, 64);
  transpose_wx<<<(9 * 128 * 16 + 255) / 256, 256, 0, stream>>>(W2x, Wx2T, 16, 16, 128);
  transpose_wx<<<(9 * 256 * 32 + 255) / 256, 256, 0, stream>>>(W3x, Wx3T, 32, 32, 256);
  transpose_wh<<<(9 * 4 * 16 * 16 + 255) / 256, 256, 0, stream>>>(W1h, Wh1T, 16);
  transpose_wh<<<(9 * 4 * 32 * 32 + 255) / 256, 256, 0, stream>>>(W2h, Wh2T, 32);
  transpose_wh<<<(9 * 4 * 64 * 64 + 255) / 256, 256, 0, stream>>>(W3h, Wh3T, 64);

  // ---- Layer 1: 64x64, Cin=3(pad 4), F=16 ----
  conv3x3_bias<64, 64, 3, 64, 4, 8, 32, 2><<<96 * 128, 256, 0, stream>>>(x, Wx1T, b1, gx1);
  {
    const long gxs = (long)T * 64 * 64 * 64;
    const long hs  = (long)T * 64 * 64 * 16;
    for (int t = 0; t < T; ++t) {
      lstm_step<64, 64, 16, 8, 8><<<B * 64, 256, 0, stream>>>(
          gx1 + (size_t)t * 64 * 64 * 64, gxs,
          t ? hseq1 + (size_t)(t - 1) * 64 * 64 * 16 : nullptr, hs,
          Wh1T, cbuf, hseq1 + (size_t)t * 64 * 64 * 16, hs, t == 0);
    }
  }
  {
    int total = B * T * 32 * 32 * 16;
    bnpool_kernel<<<(total + 255) / 256, 256, 0, stream>>>(hseq1, g1, be1, m1, v1, pool1, total, 64, 64, 16);
  }

  // ---- Layer 2: 32x32, Cin=16, F=32 ----
  conv3x3_bias<32, 32, 16, 128, 4, 8, 32, 4><<<96 * 32, 256, 0, stream>>>(pool1, Wx2T, b2, gx2);
  {
    const long gxs = (long)T * 32 * 32 * 128;
    const long hs  = (long)T * 32 * 32 * 32;
    for (int t = 0; t < T; ++t) {
      lstm_step<32, 32, 32, 4, 4><<<B * 64, 256, 0, stream>>>(
          gx2 + (size_t)t * 32 * 32 * 128, gxs,
          t ? hseq2 + (size_t)(t - 1) * 32 * 32 * 32 : nullptr, hs,
          Wh2T, cbuf, hseq2 + (size_t)t * 32 * 32 * 32, hs, t == 0);
    }
  }
  {
    int total = B * T * 16 * 16 * 32;
    bnpool_kernel<<<(total + 255) / 256, 256, 0, stream>>>(hseq2, g2, be2, m2, v2, pool2, total, 32, 32, 32);
  }

  // ---- Layer 3: 16x16, Cin=32, F=64, return last h ----
  conv3x3_bias<16, 16, 32, 256, 4, 8, 64, 4><<<96 * 8, 256, 0, stream>>>(pool2, Wx3T, b3, gx3);
  {
    const long gxs = (long)T * 16 * 16 * 256;
    const long hs  = (long)16 * 16 * 64;
    for (int t = 0; t < T; ++t) {
      float* hout = (t % 2 == 0) ? h3a : h3b;
      const float* hp = (t % 2 == 0) ? h3b : h3a;
      lstm_step<16, 16, 64, 2, 4><<<B * 32, 256, 0, stream>>>(
          gx3 + (size_t)t * 16 * 16 * 256, gxs,
          t ? hp : nullptr, hs,
          Wh3T, cbuf, hout, hs, t == 0);
    }
  }
  // final h is h3b (t=11 odd)
  poolhw_kernel<<<(32768 + 255) / 256, 256, 0, stream>>>(h3b, flat, 32768);

  // ---- Dense chain ----
  dense_partial<<<dim3(40, 64), 256, 64 * 8 * 4, stream>>>(flat, Wd1, part1, 4096, 10000, 64);
  dense_reduce<<<dim3(40, 8), 256, 0, stream>>>(part1, bd1, d1, 10000, 64);
  dense_partial<<<dim3(4, 125), 256, 80 * 8 * 4, stream>>>(d1, Wd2, part2, 10000, 1000, 80);
  dense_reduce<<<dim3(4, 8), 256, 0, stream>>>(part2, bd2, d2, 1000, 125);
  dense_small<<<(800 + 255) / 256, 256, 0, stream>>>(d2, Wd3, bd3, d3b, 1000, 100, 800);
  dense_tail<<<1, 128, 0, stream>>>(d3b, Wd4, bd4, Wc, bc, (float*)d_out);
}

// Round 6
// 1518.020 us; speedup vs baseline: 1.8661x; 1.8661x over previous
//
#include <hip/hip_runtime.h>
#include <hip/hip_bf16.h>
#include <math.h>

// ---------------------------------------------------------------------------
// Weight pre-transposes into layouts that give the hot loops float4 weight
// loads that are ALSO lane-coalesced (lane-major dim is last, 16B granules):
//   Wx (3,3,Cin,Cout) -> wxT[((tap*(CINP/4)+c4c)*Cout + co)*4 + j]   (c pad 0)
//   Wh (3,3,F,4F)     -> whT[(((tap*4+g)*(F/4)+c4c)*F + f)*4 + j]
// R5 lesson: f/co-major-then-c layouts gave float4 loads but 128-256B lane
// stride (uncoalesced gathers) -> VALUBusy 76%->30%. Lane dim must be last.
// ---------------------------------------------------------------------------
__global__ void transpose_wx(const float* __restrict__ src, float* __restrict__ dst,
                             int Cin, int CinP, int Cout)
{
  int i = blockIdx.x * 256 + threadIdx.x;
  int total = 9 * Cout * CinP;
  if (i >= total) return;
  int j = i & 3; int rem = i >> 2;
  int co = rem % Cout; rem /= Cout;
  int c4c = rem % (CinP / 4); int tap = rem / (CinP / 4);
  int c = c4c * 4 + j;
  dst[i] = (c < Cin) ? src[((size_t)tap * Cin + c) * Cout + co] : 0.f;
}

__global__ void transpose_wh(const float* __restrict__ src, float* __restrict__ dst, int F)
{
  int i = blockIdx.x * 256 + threadIdx.x;
  int total = 9 * 4 * F * F;
  if (i >= total) return;
  int j = i & 3; int rem = i >> 2;
  int f = rem % F; rem /= F;
  int c4c = rem % (F / 4); rem /= (F / 4);
  int g = rem & 3; int tap = rem >> 2;
  int c = c4c * 4 + j;
  dst[i] = src[((size_t)tap * F + c) * 4 * F + g * F + f];
}

// ---------------------------------------------------------------------------
// Direct 3x3 'SAME' conv, NHWC, fp32, with bias. Register blocking: thread
// computes NG output channels (co = tid%COL + g*COL) for PPT positions.
// Weight fetch: NG coalesced float4 loads per c4-iter.
// NOTE: `#pragma unroll 1` on the channel loop is load-bearing (R0 spill).
// ---------------------------------------------------------------------------
template<int H, int W, int Cin, int Cout, int TH, int TW, int COL, int NG>
__global__ __launch_bounds__(256) void conv3x3_bias(
    const float* __restrict__ in, const float* __restrict__ wtT,
    const float* __restrict__ bias, float* __restrict__ out)
{
  static_assert(COL * NG == Cout, "cout coverage");
  constexpr int CIN_P = (Cin % 4 == 0) ? Cin : ((Cin + 3) / 4) * 4;
  constexpr int TILES_X = W / TW, TILES_Y = H / TH;
  constexpr int PAD_W = TW + 2, PAD_H = TH + 2;
  constexpr int LDS_N = PAD_H * PAD_W * CIN_P;
  constexpr int NPG = 256 / COL;
  constexpr int PPT = TH * TW / NPG;
  __shared__ __align__(16) float tile[LDS_N];

  int blk = blockIdx.x;
  int n = blk / (TILES_X * TILES_Y);
  int trem = blk % (TILES_X * TILES_Y);
  int ty = trem / TILES_X, tx = trem % TILES_X;
  int y0 = ty * TH, x0 = tx * TW;
  const float* inN = in + (size_t)n * H * W * Cin;

  for (int i = threadIdx.x; i < LDS_N; i += 256) {
    int ci = i % CIN_P; int rem = i / CIN_P;
    int xx = rem % PAD_W; int yy = rem / PAD_W;
    int gy = y0 + yy - 1, gx = x0 + xx - 1;
    float v = 0.f;
    if (ci < Cin && gy >= 0 && gy < H && gx >= 0 && gx < W)
      v = inN[((size_t)gy * W + gx) * Cin + ci];
    tile[i] = v;
  }
  __syncthreads();

  int cobase = threadIdx.x % COL;
  int pg = threadIdx.x / COL;
  float* outN = out + (size_t)n * H * W * Cout;

  float acc[NG][PPT];
#pragma unroll
  for (int g = 0; g < NG; ++g) {
    float bco = bias[g * COL + cobase];
#pragma unroll
    for (int j = 0; j < PPT; ++j) acc[g][j] = bco;
  }

  const float4* wt4 = (const float4*)wtT;
#pragma unroll
  for (int kh = 0; kh < 3; ++kh)
#pragma unroll
  for (int kw = 0; kw < 3; ++kw) {
    const float4* wtap = wt4 + (size_t)(kh * 3 + kw) * (CIN_P / 4) * Cout;
#pragma unroll 1
    for (int c4 = 0; c4 < CIN_P; c4 += 4) {
      const float4* wrow = wtap + (size_t)(c4 / 4) * Cout + cobase;
      float4 w[NG];
#pragma unroll
      for (int g = 0; g < NG; ++g) w[g] = wrow[g * COL];
#pragma unroll
      for (int j = 0; j < PPT; ++j) {
        int p = pg * PPT + j;
        int ly = p / TW, lx = p % TW;
        const float4 h4 = *(const float4*)&tile[((ly + kh) * PAD_W + (lx + kw)) * CIN_P + c4];
#pragma unroll
        for (int g = 0; g < NG; ++g)
          acc[g][j] += h4.x * w[g].x + h4.y * w[g].y + h4.z * w[g].z + h4.w * w[g].w;
      }
    }
  }

#pragma unroll
  for (int j = 0; j < PPT; ++j) {
    int p = pg * PPT + j;
    int ly = p / TW, lx = p % TW;
    float* op = &outN[((size_t)(y0 + ly) * W + (x0 + lx)) * Cout + cobase];
#pragma unroll
    for (int g = 0; g < NG; ++g) op[g * COL] = acc[g][j];
  }
}

// ---------------------------------------------------------------------------
// One ConvLSTM timestep: z = gx[t] + conv3x3(h_prev, WhT); gates i,f,c,o;
// c = hs(zf)*c + hs(zi)*tanh(zc); h = hs(zo)*tanh(c).
// Thread owns one f across all 4 gates, NP positions. Weight fetch: 4
// coalesced float4 loads per c4-iter.
// ---------------------------------------------------------------------------
__device__ __forceinline__ float hsig(float x) {
  return fminf(fmaxf(0.2f * x + 0.5f, 0.f), 1.f);
}

template<int H, int W, int F, int TH, int TW>
__global__ __launch_bounds__(256) void lstm_step(
    const float* __restrict__ gx, long gx_bstride,     // pre-offset to slice t
    const float* __restrict__ hprev, long hp_bstride,  // null when first
    const float* __restrict__ whT,                     // packed, see transpose_wh
    float* __restrict__ c,
    float* __restrict__ hout, long ho_bstride,
    int first)
{
  constexpr int TILES_X = W / TW, TILES_Y = H / TH;
  constexpr int PAD_W = TW + 2, PAD_H = TH + 2;
  constexpr int LDS_N = PAD_H * PAD_W * F;
  __shared__ __align__(16) float tile[LDS_N];

  int blk = blockIdx.x;
  int b = blk / (TILES_X * TILES_Y);
  int trem = blk % (TILES_X * TILES_Y);
  int ty = trem / TILES_X, tx = trem % TILES_X;
  int y0 = ty * TH, x0 = tx * TW;

  if (first) {
    for (int i = threadIdx.x; i < LDS_N; i += 256) tile[i] = 0.f;
  } else {
    const float* hb = hprev + (size_t)b * hp_bstride;
    for (int i = threadIdx.x; i < LDS_N; i += 256) {
      int ci = i % F; int rem = i / F;
      int xx = rem % PAD_W, yy = rem / PAD_W;
      int gy = y0 + yy - 1, gxp = x0 + xx - 1;
      float v = 0.f;
      if (gy >= 0 && gy < H && gxp >= 0 && gxp < W)
        v = hb[((size_t)gy * W + gxp) * F + ci];
      tile[i] = v;
    }
  }
  __syncthreads();

  constexpr int G = 256 / F;     // position-groups
  constexpr int P = TH * TW;
  constexpr int NP = P / G;      // positions per thread
  int f = threadIdx.x % F;
  int pg = threadIdx.x / F;

  float acc[4][NP];
  const float* gxb = gx + (size_t)b * gx_bstride;
#pragma unroll
  for (int j = 0; j < NP; ++j) {
    int p = pg * NP + j;
    int gy = y0 + p / TW, gxp = x0 + p % TW;
    size_t base = ((size_t)gy * W + gxp) * 4 * F;
#pragma unroll
    for (int g = 0; g < 4; ++g) acc[g][j] = gxb[base + g * F + f];
  }

  const float4* wh4 = (const float4*)whT;
#pragma unroll
  for (int kh = 0; kh < 3; ++kh)
#pragma unroll
  for (int kw = 0; kw < 3; ++kw) {
    int tap = kh * 3 + kw;
#pragma unroll 1
    for (int c4 = 0; c4 < F; c4 += 4) {
      float4 h4[NP];
#pragma unroll
      for (int j = 0; j < NP; ++j) {
        int p = pg * NP + j;
        int ly = p / TW, lx = p % TW;
        h4[j] = *(const float4*)&tile[((ly + kh) * PAD_W + (lx + kw)) * F + c4];
      }
      // coalesced: consecutive f lanes -> consecutive float4
      float4 w0 = wh4[((size_t)(tap * 4 + 0) * (F / 4) + c4 / 4) * F + f];
      float4 w1 = wh4[((size_t)(tap * 4 + 1) * (F / 4) + c4 / 4) * F + f];
      float4 w2 = wh4[((size_t)(tap * 4 + 2) * (F / 4) + c4 / 4) * F + f];
      float4 w3 = wh4[((size_t)(tap * 4 + 3) * (F / 4) + c4 / 4) * F + f];
#pragma unroll
      for (int j = 0; j < NP; ++j) {
        acc[0][j] += h4[j].x * w0.x + h4[j].y * w0.y + h4[j].z * w0.z + h4[j].w * w0.w;
        acc[1][j] += h4[j].x * w1.x + h4[j].y * w1.y + h4[j].z * w1.z + h4[j].w * w1.w;
        acc[2][j] += h4[j].x * w2.x + h4[j].y * w2.y + h4[j].z * w2.z + h4[j].w * w2.w;
        acc[3][j] += h4[j].x * w3.x + h4[j].y * w3.y + h4[j].z * w3.z + h4[j].w * w3.w;
      }
    }
  }

  float* cb = c + (size_t)b * H * W * F;
  float* hb2 = hout + (size_t)b * ho_bstride;
#pragma unroll
  for (int j = 0; j < NP; ++j) {
    int p = pg * NP + j;
    int gy = y0 + p / TW, gxp = x0 + p % TW;
    size_t idx = ((size_t)gy * W + gxp) * F + f;
    float zi = acc[0][j], zf = acc[1][j], zc = acc[2][j], zo = acc[3][j];
    float cold = first ? 0.f : cb[idx];
    float cn = hsig(zf) * cold + hsig(zi) * tanhf(zc);
    cb[idx] = cn;
    hb2[idx] = hsig(zo) * tanhf(cn);
  }
}

// ---------------------------------------------------------------------------
// BatchNorm (affine, eps=1e-3) + 2x2 spatial max.
// ---------------------------------------------------------------------------
__global__ void bnpool_kernel(const float* __restrict__ in,
                              const float* __restrict__ g, const float* __restrict__ be,
                              const float* __restrict__ m, const float* __restrict__ v,
                              float* __restrict__ out, int total, int H, int W, int F)
{
  int i = blockIdx.x * 256 + threadIdx.x;
  if (i >= total) return;
  int f = i % F; int rem = i / F;
  int x = rem % (W / 2); rem /= (W / 2);
  int y = rem % (H / 2); int nt = rem / (H / 2);
  float scale = g[f] * rsqrtf(v[f] + 1e-3f);
  float shift = be[f] - m[f] * scale;
  const float* base = in + (((size_t)nt * H + 2 * y) * W + 2 * x) * F + f;
  float a0 = base[0] * scale + shift;
  float a1 = base[F] * scale + shift;
  float a2 = base[(size_t)W * F] * scale + shift;
  float a3 = base[(size_t)W * F + F] * scale + shift;
  out[i] = fmaxf(fmaxf(a0, a1), fmaxf(a2, a3));
}

// (8,16,16,64) -> (8,8,8,64) flattened to (8,4096)
__global__ void poolhw_kernel(const float* __restrict__ in, float* __restrict__ out, int total)
{
  int i = blockIdx.x * 256 + threadIdx.x;
  if (i >= total) return;
  int f = i % 64; int rem = i / 64;
  int x = rem % 8; rem /= 8;
  int y = rem % 8; int b = rem / 8;
  const float* base = in + (((size_t)b * 16 + 2 * y) * 16 + 2 * x) * 64 + f;
  float a0 = base[0], a1 = base[64], a2 = base[16 * 64], a3 = base[16 * 64 + 64];
  out[i] = fmaxf(fmaxf(a0, a1), fmaxf(a2, a3));
}

// ---------------------------------------------------------------------------
// Dense (8,K)@(K,N): k-split partials + reduce (no atomics).
// ---------------------------------------------------------------------------
__global__ __launch_bounds__(256) void dense_partial(
    const float* __restrict__ x, const float* __restrict__ w,
    float* __restrict__ part, int K, int N, int kchunk)
{
  extern __shared__ __align__(16) float xs[];  // kchunk*8, layout [kk][b]
  int kb = blockIdx.y;
  int k0 = kb * kchunk;
  int klen = min(kchunk, K - k0);
  for (int i = threadIdx.x; i < klen * 8; i += 256) {
    int kk = i >> 3, b = i & 7;
    xs[i] = x[(size_t)b * K + k0 + kk];
  }
  __syncthreads();
  int co = blockIdx.x * 256 + threadIdx.x;
  if (co >= N) return;
  float acc[8];
#pragma unroll
  for (int b = 0; b < 8; ++b) acc[b] = 0.f;
  const float4* xs4 = (const float4*)xs;
  const float* wp = w + (size_t)k0 * N + co;
#pragma unroll 4
  for (int kk = 0; kk < klen; ++kk) {
    float wv = wp[(size_t)kk * N];
    float4 lo = xs4[kk * 2], hi = xs4[kk * 2 + 1];
    acc[0] += lo.x * wv; acc[1] += lo.y * wv;
    acc[2] += lo.z * wv; acc[3] += lo.w * wv;
    acc[4] += hi.x * wv; acc[5] += hi.y * wv;
    acc[6] += hi.z * wv; acc[7] += hi.w * wv;
  }
#pragma unroll
  for (int b = 0; b < 8; ++b)
    part[((size_t)kb * 8 + b) * N + co] = acc[b];
}

__global__ __launch_bounds__(256) void dense_reduce(
    const float* __restrict__ part, const float* __restrict__ bias,
    float* __restrict__ out, int N, int S)
{
  int co = blockIdx.x * 256 + threadIdx.x;
  int b = blockIdx.y;
  if (co >= N) return;
  float acc = bias[co];
#pragma unroll 4
  for (int kb = 0; kb < S; ++kb)
    acc += part[((size_t)kb * 8 + b) * N + co];
  out[(size_t)b * N + co] = acc;
}

// Direct small dense: one thread per (b,co). Used for 1000->100.
__global__ void dense_small(const float* __restrict__ x, const float* __restrict__ w,
                            const float* __restrict__ bias, float* __restrict__ out,
                            int K, int N, int total)
{
  int idx = blockIdx.x * 256 + threadIdx.x;
  if (idx >= total) return;
  int b = idx / N, co = idx % N;
  float acc = bias[co];
  const float* xb = x + (size_t)b * K;
#pragma unroll 4
  for (int k = 0; k < K; ++k) acc += xb[k] * w[(size_t)k * N + co];
  out[idx] = acc;
}

// Final (8,100)@(100,10)+b4 then @(10,1)+bc -> (8,1)
__global__ void dense_tail(const float* __restrict__ d3,
                           const float* __restrict__ w4, const float* __restrict__ b4,
                           const float* __restrict__ wc, const float* __restrict__ bc,
                           float* __restrict__ out)
{
  __shared__ float d4[8][10];
  int t = threadIdx.x;
  if (t < 80) {
    int b = t / 10, co = t % 10;
    float acc = b4[co];
    for (int k = 0; k < 100; ++k) acc += d3[b * 100 + k] * w4[k * 10 + co];
    d4[b][co] = acc;
  }
  __syncthreads();
  if (t < 8) {
    float acc = bc[0];
    for (int j = 0; j < 10; ++j) acc += d4[t][j] * wc[j];
    out[t] = acc;
  }
}

// ---------------------------------------------------------------------------
extern "C" void kernel_launch(void* const* d_in, const int* in_sizes, int n_in,
                              void* d_out, int out_size, void* d_ws, size_t ws_size,
                              hipStream_t stream)
{
  const float* x   = (const float*)d_in[0];
  const float* W1x = (const float*)d_in[1];
  const float* W1h = (const float*)d_in[2];
  const float* b1  = (const float*)d_in[3];
  const float* g1  = (const float*)d_in[4];
  const float* be1 = (const float*)d_in[5];
  const float* m1  = (const float*)d_in[6];
  const float* v1  = (const float*)d_in[7];
  const float* W2x = (const float*)d_in[8];
  const float* W2h = (const float*)d_in[9];
  const float* b2  = (const float*)d_in[10];
  const float* g2  = (const float*)d_in[11];
  const float* be2 = (const float*)d_in[12];
  const float* m2  = (const float*)d_in[13];
  const float* v2  = (const float*)d_in[14];
  const float* W3x = (const float*)d_in[15];
  const float* W3h = (const float*)d_in[16];
  const float* b3  = (const float*)d_in[17];
  const float* Wd1 = (const float*)d_in[18];
  const float* bd1 = (const float*)d_in[19];
  const float* Wd2 = (const float*)d_in[20];
  const float* bd2 = (const float*)d_in[21];
  const float* Wd3 = (const float*)d_in[22];
  const float* bd3 = (const float*)d_in[23];
  const float* Wd4 = (const float*)d_in[24];
  const float* bd4 = (const float*)d_in[25];
  const float* Wc  = (const float*)d_in[26];
  const float* bc  = (const float*)d_in[27];

  // workspace layout (bytes, 256-aligned), lifetime-based reuse
  char* ws = (char*)d_ws;
  size_t off = 0;
  auto alloc = [&](size_t bytes) { size_t r = off; off = (off + bytes + 255) & ~(size_t)255; return r; };
  size_t oR0    = alloc(100663296);  // gx1 -> gx2 -> gx3; then part1/part2 for dense
  size_t oR1    = alloc(25165824);   // hseq1 -> hseq2
  size_t oR2    = alloc(6291456);    // pool1 -> pool2
  size_t oR3    = alloc(2097152);    // c buffer
  size_t oh3a   = alloc(524288);
  size_t oh3b   = alloc(524288);
  size_t oflat  = alloc(131072);
  size_t od1    = alloc(320000);
  size_t od2    = alloc(32000);
  size_t od3    = alloc(3200);
  size_t oWx1T  = alloc(9216);      // 9*64*4
  size_t oWx2T  = alloc(73728);     // 9*128*16
  size_t oWx3T  = alloc(294912);    // 9*256*32
  size_t oWh1T  = alloc(36864);     // 9*4*16*16
  size_t oWh2T  = alloc(147456);    // 9*4*32*32
  size_t oWh3T  = alloc(589824);    // 9*4*64*64
  (void)ws_size; (void)in_sizes; (void)n_in; (void)out_size;

  float* gx1   = (float*)(ws + oR0);
  float* gx2   = (float*)(ws + oR0);
  float* gx3   = (float*)(ws + oR0);
  float* part1 = (float*)(ws + oR0);             // 64*8*10000*4 = 20.5 MB (gx dead)
  float* part2 = (float*)(ws + oR0 + 33554432);  // 125*8*1000*4 = 4 MB
  float* hseq1 = (float*)(ws + oR1);
  float* hseq2 = (float*)(ws + oR1);
  float* pool1 = (float*)(ws + oR2);
  float* pool2 = (float*)(ws + oR2);
  float* cbuf  = (float*)(ws + oR3);
  float* h3a   = (float*)(ws + oh3a);
  float* h3b   = (float*)(ws + oh3b);
  float* flat  = (float*)(ws + oflat);
  float* d1    = (float*)(ws + od1);
  float* d2    = (float*)(ws + od2);
  float* d3b   = (float*)(ws + od3);
  float* Wx1T  = (float*)(ws + oWx1T);
  float* Wx2T  = (float*)(ws + oWx2T);
  float* Wx3T  = (float*)(ws + oWx3T);
  float* Wh1T  = (float*)(ws + oWh1T);
  float* Wh2T  = (float*)(ws + oWh2T);
  float* Wh3T  = (float*)(ws + oWh3T);

  const int B = 8, T = 12;

  // ---- Weight transposes (tiny) ----
  transpose_wx<<<(9 * 64 * 4 + 255) / 256, 256, 0, stream>>>(W1x, Wx1T, 3, 4, 64);
  transpose_wx<<<(9 * 128 * 16 + 255) / 256, 256, 0, stream>>>(W2x, Wx2T, 16, 16, 128);
  transpose_wx<<<(9 * 256 * 32 + 255) / 256, 256, 0, stream>>>(W3x, Wx3T, 32, 32, 256);
  transpose_wh<<<(9 * 4 * 16 * 16 + 255) / 256, 256, 0, stream>>>(W1h, Wh1T, 16);
  transpose_wh<<<(9 * 4 * 32 * 32 + 255) / 256, 256, 0, stream>>>(W2h, Wh2T, 32);
  transpose_wh<<<(9 * 4 * 64 * 64 + 255) / 256, 256, 0, stream>>>(W3h, Wh3T, 64);

  // ---- Layer 1: 64x64, Cin=3(pad 4), F=16 ----
  conv3x3_bias<64, 64, 3, 64, 4, 8, 32, 2><<<96 * 128, 256, 0, stream>>>(x, Wx1T, b1, gx1);
  {
    const long gxs = (long)T * 64 * 64 * 64;
    const long hs  = (long)T * 64 * 64 * 16;
    for (int t = 0; t < T; ++t) {
      lstm_step<64, 64, 16, 8, 8><<<B * 64, 256, 0, stream>>>(
          gx1 + (size_t)t * 64 * 64 * 64, gxs,
          t ? hseq1 + (size_t)(t - 1) * 64 * 64 * 16 : nullptr, hs,
          Wh1T, cbuf, hseq1 + (size_t)t * 64 * 64 * 16, hs, t == 0);
    }
  }
  {
    int total = B * T * 32 * 32 * 16;
    bnpool_kernel<<<(total + 255) / 256, 256, 0, stream>>>(hseq1, g1, be1, m1, v1, pool1, total, 64, 64, 16);
  }

  // ---- Layer 2: 32x32, Cin=16, F=32 ----
  conv3x3_bias<32, 32, 16, 128, 4, 8, 32, 4><<<96 * 32, 256, 0, stream>>>(pool1, Wx2T, b2, gx2);
  {
    const long gxs = (long)T * 32 * 32 * 128;
    const long hs  = (long)T * 32 * 32 * 32;
    for (int t = 0; t < T; ++t) {
      lstm_step<32, 32, 32, 4, 4><<<B * 64, 256, 0, stream>>>(
          gx2 + (size_t)t * 32 * 32 * 128, gxs,
          t ? hseq2 + (size_t)(t - 1) * 32 * 32 * 32 : nullptr, hs,
          Wh2T, cbuf, hseq2 + (size_t)t * 32 * 32 * 32, hs, t == 0);
    }
  }
  {
    int total = B * T * 16 * 16 * 32;
    bnpool_kernel<<<(total + 255) / 256, 256, 0, stream>>>(hseq2, g2, be2, m2, v2, pool2, total, 32, 32, 32);
  }

  // ---- Layer 3: 16x16, Cin=32, F=64, return last h ----
  conv3x3_bias<16, 16, 32, 256, 4, 8, 64, 4><<<96 * 8, 256, 0, stream>>>(pool2, Wx3T, b3, gx3);
  {
    const long gxs = (long)T * 16 * 16 * 256;
    const long hs  = (long)16 * 16 * 64;
    for (int t = 0; t < T; ++t) {
      float* hout = (t % 2 == 0) ? h3a : h3b;
      const float* hp = (t % 2 == 0) ? h3b : h3a;
      lstm_step<16, 16, 64, 2, 4><<<B * 32, 256, 0, stream>>>(
          gx3 + (size_t)t * 16 * 16 * 256, gxs,
          t ? hp : nullptr, hs,
          Wh3T, cbuf, hout, hs, t == 0);
    }
  }
  // final h is h3b (t=11 odd)
  poolhw_kernel<<<(32768 + 255) / 256, 256, 0, stream>>>(h3b, flat, 32768);

  // ---- Dense chain ----
  dense_partial<<<dim3(40, 64), 256, 64 * 8 * 4, stream>>>(flat, Wd1, part1, 4096, 10000, 64);
  dense_reduce<<<dim3(40, 8), 256, 0, stream>>>(part1, bd1, d1, 10000, 64);
  dense_partial<<<dim3(4, 125), 256, 80 * 8 * 4, stream>>>(d1, Wd2, part2, 10000, 1000, 80);
  dense_reduce<<<dim3(4, 8), 256, 0, stream>>>(part2, bd2, d2, 1000, 125);
  dense_small<<<(800 + 255) / 256, 256, 0, stream>>>(d2, Wd3, bd3, d3b, 1000, 100, 800);
  dense_tail<<<1, 128, 0, stream>>>(d3b, Wd4, bd4, Wc, bc, (float*)d_out);
}